// Round 3
// baseline (487.330 us; speedup 1.0000x reference)
//
#include <hip/hip_runtime.h>

// ---------------------------------------------------------------------------
// ZSSR involution net, all fp32.
// conv_in(3->64,3x3,p2) -> 6x [w_kernel -> e_kernel] -> conv_out+PixelShuffle
// ---------------------------------------------------------------------------

#define H2 130
#define PLANE (H2*H2)          // 16900
#define XBUF (64*PLANE)        // 1,081,600 floats
#define WPLANE (132*132)       // 17424 (padded w plane, 16B-aligned rows)

#define OFF_X0 0
#define OFF_X1 XBUF
#define OFF_WF (2*XBUF)        // w-field: 196*17424 = 3,415,104 floats

// --- conv_in: 3->64, 3x3, pad=2 : (3,128,128) -> (64,130,130) --------------
__global__ __launch_bounds__(256) void conv_in_kernel(
        const float* __restrict__ inf, const float* __restrict__ W,
        const float* __restrict__ b, float* __restrict__ x0) {
    const int c = blockIdx.y;                       // wave-uniform
    int p = blockIdx.x * 256 + threadIdx.x;
    if (p >= PLANE) return;
    int h = p / H2, w = p % H2;
    float acc = b[c];
    #pragma unroll
    for (int i = 0; i < 3; ++i)
        #pragma unroll
        for (int ky = 0; ky < 3; ++ky) {
            int y = h - 2 + ky;
            if ((unsigned)y >= 128u) continue;
            #pragma unroll
            for (int kx = 0; kx < 3; ++kx) {
                int x = w - 2 + kx;
                if ((unsigned)x >= 128u) continue;
                acc += W[((c*3 + i)*3 + ky)*3 + kx] * inf[i*16384 + y*128 + x];
            }
        }
    x0[c*PLANE + p] = acc;
}

// --- w_kernel: per-pixel dynamic kernel generation -------------------------
// 256 thr = 64 px * 4 group-waves. t in LDS, w-field out (padded planes).
__global__ __launch_bounds__(256) void w_kernel(
        const float* __restrict__ x, float* __restrict__ wf,
        const float* __restrict__ redw,   // [16][64]
        const float* __restrict__ gamma, const float* __restrict__ beta,
        const float* __restrict__ spanw,  // [196][16]
        const float* __restrict__ spanb)  // [196]
{
    __shared__ float t_lds[64*17];
    const int tid = threadIdx.x;
    const int pix = tid & 63;
    const int g = __builtin_amdgcn_readfirstlane(tid >> 6);
    int px = blockIdx.x*64 + pix;
    int pxc = px < PLANE ? px : PLANE-1;

    // phase A: t[4g..4g+3] for this pixel
    const float* rw = redw + g*256;
    float a0=0.f, a1=0.f, a2=0.f, a3=0.f;
    for (int c = 0; c < 64; ++c) {
        float xv = x[c*PLANE + pxc];
        a0 += rw[c]      * xv;
        a1 += rw[64 + c] * xv;
        a2 += rw[128 + c]* xv;
        a3 += rw[192 + c]* xv;
    }
    int r0 = g*4;
    t_lds[pix*17 + r0 + 0] = fmaxf(gamma[r0+0]*a0 + beta[r0+0], 0.f);
    t_lds[pix*17 + r0 + 1] = fmaxf(gamma[r0+1]*a1 + beta[r0+1], 0.f);
    t_lds[pix*17 + r0 + 2] = fmaxf(gamma[r0+2]*a2 + beta[r0+2], 0.f);
    t_lds[pix*17 + r0 + 3] = fmaxf(gamma[r0+3]*a3 + beta[r0+3], 0.f);
    __syncthreads();

    // phase B: 49 w-channels for (pixel, g)
    float t16[16];
    #pragma unroll
    for (int r = 0; r < 16; ++r) t16[r] = t_lds[pix*17 + r];
    const bool ok = px < PLANE;
    int row = pxc / 130, col = pxc % 130;
    const float* sw = spanw + g*49*16;
    const float* sb = spanb + g*49;
    float* wbase = wf + (size_t)(g*49)*WPLANE + row*132 + col;
    #pragma unroll 7
    for (int k = 0; k < 49; ++k) {
        float acc = sb[k];
        #pragma unroll
        for (int r = 0; r < 16; ++r) acc += sw[k*16 + r] * t16[r];
        if (ok) wbase[(size_t)k*WPLANE] = acc;
    }
}

// --- e_kernel: the per-pixel 7x7 dynamic conv (einsum) + ReLU --------------
// WG = (group g = blockIdx.z, 16x16 tile). 256 thr = 64 strips * 4 ch-quads.
// x halo [16][22][24] in LDS (b128-aligned rows); w read as float4 from wf.
__global__ __launch_bounds__(256) void e_kernel(
        const float* __restrict__ x, const float* __restrict__ wf,
        float* __restrict__ xout)
{
    __shared__ float xl[16*528];   // [16 ch][22 rows][24 cols] = 33.8 KB
    const int tid = threadIdx.x;
    const int g = blockIdx.z;
    const int ty = blockIdx.y*16, tx = blockIdx.x*16;

    for (int idx = tid; idx < 16*484; idx += 256) {
        int c = idx / 484, rem = idx % 484;
        int r = rem / 22, cl = rem % 22;
        int gy = ty - 3 + r, gx = tx - 3 + cl;
        float v = 0.f;
        if ((unsigned)gy < (unsigned)H2 && (unsigned)gx < (unsigned)H2)
            v = x[(g*16 + c)*PLANE + gy*H2 + gx];
        xl[c*528 + r*24 + cl] = v;
    }
    __syncthreads();

    const int s = tid & 63, cq = tid >> 6;
    const int srow = s >> 2, scol = s & 3;
    const int c0 = cq*4;
    float acc[4][4] = {};

    const float* wrow = wf + (size_t)(g*49)*WPLANE + (ty + srow)*132 + tx + scol*4;
    #pragma unroll
    for (int i = 0; i < 7; ++i) {
        float4 w7[7];
        #pragma unroll
        for (int j = 0; j < 7; ++j)
            w7[j] = *(const float4*)(wrow + (size_t)(i*7 + j)*WPLANE);
        #pragma unroll
        for (int cc = 0; cc < 4; ++cc) {
            const float* xb = &xl[(c0 + cc)*528 + (srow + i)*24 + scol*4];
            float4 xa = *(const float4*)(xb);
            float4 xm = *(const float4*)(xb + 4);
            float4 xz = *(const float4*)(xb + 8);
            float xr[12] = {xa.x,xa.y,xa.z,xa.w, xm.x,xm.y,xm.z,xm.w,
                            xz.x,xz.y,xz.z,xz.w};
            #pragma unroll
            for (int j = 0; j < 7; ++j) {
                acc[cc][0] += w7[j].x * xr[j+0];
                acc[cc][1] += w7[j].y * xr[j+1];
                acc[cc][2] += w7[j].z * xr[j+2];
                acc[cc][3] += w7[j].w * xr[j+3];
            }
        }
    }

    const int h = ty + srow;
    #pragma unroll
    for (int cc = 0; cc < 4; ++cc) {
        float* dst = xout + (size_t)(g*16 + c0 + cc)*PLANE + h*H2 + tx + scol*4;
        #pragma unroll
        for (int q = 0; q < 4; ++q) {
            int w = tx + scol*4 + q;
            if (h < H2 && w < H2) dst[q] = fmaxf(acc[cc][q], 0.f);
        }
    }
}

// --- conv_out (64->12, 3x3 valid) + PixelShuffle(2) ------------------------
// WG = 8x8 out tile (grid 16x16). 256 thr: wave = 3 o's, lane = (strip, cq).
// x halo [64][10][12] + all weights in LDS; shfl-reduce over 4 c-chunks.
__global__ __launch_bounds__(256) void conv_out_ps_kernel(
        const float* __restrict__ x, const float* __restrict__ W,
        const float* __restrict__ b, float* __restrict__ out)
{
    __shared__ float xh[64*120];   // 7680 floats
    __shared__ float wl[6912];     // 12*64*9
    const int tid = threadIdx.x;
    const int ty = blockIdx.y*8, tx = blockIdx.x*8;

    for (int idx = tid; idx < 6912; idx += 256) wl[idx] = W[idx];
    for (int idx = tid; idx < 7680; idx += 256) {
        int c = idx / 120, rem = idx % 120;
        int r = rem / 12, cl = rem % 12;
        float v = 0.f;
        if (cl < 10) v = x[c*PLANE + (ty + r)*H2 + tx + cl];
        xh[idx] = v;
    }
    __syncthreads();

    const int wave = __builtin_amdgcn_readfirstlane(tid >> 6);
    const int lane = tid & 63;
    const int s = lane >> 2, cq = lane & 3;
    const int sr = s >> 1, pc0 = (s & 1)*4;
    float acc[3][4] = {};

    for (int c = cq*16; c < cq*16 + 16; ++c) {
        #pragma unroll
        for (int ky = 0; ky < 3; ++ky) {
            const float* xb = &xh[c*120 + (sr + ky)*12 + pc0];
            float4 xa = *(const float4*)xb;
            float2 xm = *(const float2*)(xb + 4);
            float xr[6] = {xa.x, xa.y, xa.z, xa.w, xm.x, xm.y};
            #pragma unroll
            for (int oj = 0; oj < 3; ++oj) {
                const float* wp = &wl[((wave*3 + oj)*64 + c)*9 + ky*3];
                #pragma unroll
                for (int kx = 0; kx < 3; ++kx) {
                    float wv = wp[kx];
                    #pragma unroll
                    for (int q = 0; q < 4; ++q)
                        acc[oj][q] += wv * xr[kx + q];
                }
            }
        }
    }

    #pragma unroll
    for (int oj = 0; oj < 3; ++oj)
        #pragma unroll
        for (int q = 0; q < 4; ++q) {
            float v = acc[oj][q];
            v += __shfl_xor(v, 1, 64);
            v += __shfl_xor(v, 2, 64);
            acc[oj][q] = v;
        }

    if (cq == 0) {
        #pragma unroll
        for (int oj = 0; oj < 3; ++oj) {
            int o = wave*3 + oj;
            float bo = b[o];
            int c3 = o >> 2, r = (o >> 1) & 1, s2 = o & 1;
            int h = ty + sr;
            #pragma unroll
            for (int q = 0; q < 4; ++q) {
                int w = tx + pc0 + q;
                out[c3*65536 + (2*h + r)*256 + 2*w + s2] = acc[oj][q] + bo;
            }
        }
    }
}

// ---------------------------------------------------------------------------
extern "C" void kernel_launch(void* const* d_in, const int* in_sizes, int n_in,
                              void* d_out, int out_size, void* d_ws, size_t ws_size,
                              hipStream_t stream) {
    const float* inf   = (const float*)d_in[0];
    const float* cinw  = (const float*)d_in[1];
    const float* cinb  = (const float*)d_in[2];
    const float* redw  = (const float*)d_in[3];
    const float* gam   = (const float*)d_in[4];
    const float* bet   = (const float*)d_in[5];
    const float* spw   = (const float*)d_in[6];
    const float* spb   = (const float*)d_in[7];
    const float* cow   = (const float*)d_in[8];
    const float* cob   = (const float*)d_in[9];

    float* ws = (float*)d_ws;
    float* x0 = ws + OFF_X0;
    float* x1 = ws + OFF_X1;
    float* wfield = ws + OFF_WF;

    conv_in_kernel<<<dim3((PLANE + 255)/256, 64), 256, 0, stream>>>(
        inf, cinw, cinb, x0);

    float* cur = x0; float* nxt = x1;
    for (int l = 0; l < 6; ++l) {
        w_kernel<<<(PLANE + 63)/64, 256, 0, stream>>>(
            cur, wfield,
            redw + l*1024, gam + l*16, bet + l*16,
            spw + l*3136, spb + l*196);
        e_kernel<<<dim3(9, 9, 4), 256, 0, stream>>>(cur, wfield, nxt);
        float* t = cur; cur = nxt; nxt = t;
    }

    conv_out_ps_kernel<<<dim3(16, 16), 256, 0, stream>>>(
        cur, cow, cob, (float*)d_out);
}